// Round 8
// baseline (191.944 us; speedup 1.0000x reference)
//
#include <hip/hip_runtime.h>
#include <cstdint>
#include <cstddef>

#define NB 8
#define NL 2048
#define TOPK 30
#define NH 128
#define CAND_CAP 256

typedef unsigned long long ull;
typedef __attribute__((ext_vector_type(8))) short short8v;   // 8 bf16
typedef __attribute__((ext_vector_type(4))) float f32x4;

__device__ __forceinline__ short f2bf(float f) {
    unsigned int b = __float_as_uint(f);
    b += 0x7fffu + ((b >> 16) & 1u);          // round-to-nearest-even
    return (short)(b >> 16);
}

// ---------------------------------------------------------------------------
// K0: pack CA coords + mask into SoA float4 (x,y,z,m) for coalesced topk loads.
// ---------------------------------------------------------------------------
__global__ __launch_bounds__(256) void xpose_kernel(
    const float* __restrict__ X, const float* __restrict__ mask,
    float4* __restrict__ P)
{
    int t = blockIdx.x * blockDim.x + threadIdx.x;
    if (t >= NB * NL) return;
    const float* p = X + (size_t)t * 12 + 3;
    P[t] = make_float4(p[0], p[1], p[2], mask[t]);
}

// ---------------------------------------------------------------------------
// K1 (v5): one WAVE per row, register-resident, NO histogram.
// Each lane owns 32 points; distance computed once, bit-exact vs numpy
// (((dx*dx+dy*dy)+dz*dz)+1e-6, rn sqrt, rn muls). Mask flag rides the sign
// bit; adjusted value = select(D, Dmax+1).
// Threshold: T = 30th-smallest of the 64 lane-minima (bitonic sort via
// shfl_xor). Guarantee: >=30 lanes have min <= T => >=30 values <= T =>
// all true top-30 <= T. Ballot-compact u<=T (index-ordered), rank-select.
// Key = (bits<<32)|j == lax.top_k stable tie order. Exact fallback if
// candidates overflow CAND_CAP.
// ---------------------------------------------------------------------------
__global__ __launch_bounds__(256) void topk_kernel(
    const float4* __restrict__ P,
    float* __restrict__ eidx, float* __restrict__ dnb)
{
    __shared__ ull cand[4][CAND_CAP];              // 8 KB

    const int tid = threadIdx.x;
    const int wv  = tid >> 6;
    const int ln  = tid & 63;
    const int row = blockIdx.x * 4 + wv;           // 4 consecutive rows/block
    const int b   = row >> 11;
    const int i   = row & (NL - 1);

    const float4* Pb = P + (size_t)b * NL;
    const float4 pi = Pb[i];
    const float xi = pi.x, yi = pi.y, zi = pi.z, mi = pi.w;

    // ---- P1: distances once; pack mask flag into sign bit ----
    unsigned int u[32];
    float lmax = 0.0f;
    #pragma unroll
    for (int t = 0; t < 32; ++t) {
        const float4 pj = Pb[ln + 64 * t];
        float dx = xi - pj.x;
        float dy = yi - pj.y;
        float dz = zi - pj.z;
        float s = __fadd_rn(__fmul_rn(dx, dx), __fmul_rn(dy, dy));
        s = __fadd_rn(s, __fmul_rn(dz, dz));
        s = __fadd_rn(s, 1e-6f);
        float m2 = __fmul_rn(pj.w, mi);            // binary mask: 0 or 1
        float d  = __fmul_rn(m2, __fsqrt_rn(s));
        u[t] = __float_as_uint(d) | ((m2 == 0.0f) ? 0x80000000u : 0u);
        lmax = fmaxf(lmax, d);
    }
    #pragma unroll
    for (int off = 32; off; off >>= 1) lmax = fmaxf(lmax, __shfl_xor(lmax, off));
    const unsigned int DMB = __float_as_uint(__fadd_rn(lmax, 1.0f));

    // ---- P2: adjusted bits via select + per-lane min ----
    unsigned int umin = 0xFFFFFFFFu;
    #pragma unroll
    for (int t = 0; t < 32; ++t) {
        unsigned int bt = (u[t] & 0x80000000u) ? DMB : u[t];
        u[t] = bt;
        umin = min(umin, bt);
    }

    // ---- P3: bitonic sort of 64 lane-minima -> threshold T at rank 29 ----
    unsigned int v = umin;
    #pragma unroll
    for (int k = 2; k <= 64; k <<= 1) {
        #pragma unroll
        for (int j = k >> 1; j > 0; j >>= 1) {
            unsigned int o = __shfl_xor(v, j);
            bool asc   = ((ln & k) == 0);
            bool lower = ((ln & j) == 0);
            v = (lower == asc) ? min(v, o) : max(v, o);
        }
    }
    const unsigned int T = __shfl(v, TOPK - 1);

    // ---- P4: ordered ballot compaction (index-sorted: t outer, lane inner) ----
    unsigned int base = 0;
    #pragma unroll
    for (int t = 0; t < 32; ++t) {
        bool act = u[t] <= T;
        ull m = __ballot(act);
        if (act) {
            unsigned int pos = base + (unsigned)__popcll(m & ((1ull << ln) - 1ull));
            if (pos < CAND_CAP)
                cand[wv][pos] = ((ull)u[t] << 32) | (unsigned)(ln + 64 * t);
        }
        base += (unsigned)__popcll(m);
    }
    const unsigned int cnt = base;

    float* eo  = eidx + (size_t)row * TOPK;
    float* dno = dnb  + (size_t)row * TOPK;

    if (cnt <= CAND_CAP) {
        // ---- P5: rank-based exact selection ----
        ull k0 = ((unsigned)ln        < cnt) ? cand[wv][ln]        : ~0ULL;
        ull k1 = ((unsigned)ln +  64u < cnt) ? cand[wv][ln +  64]  : ~0ULL;
        ull k2 = ((unsigned)ln + 128u < cnt) ? cand[wv][ln + 128]  : ~0ULL;
        ull k3 = ((unsigned)ln + 192u < cnt) ? cand[wv][ln + 192]  : ~0ULL;
        int r0 = 0, r1 = 0, r2 = 0, r3 = 0;
        for (unsigned int p = 0; p < cnt; ++p) {
            ull kp = cand[wv][p];
            r0 += (kp < k0); r1 += (kp < k1); r2 += (kp < k2); r3 += (kp < k3);
        }
        if (r0 < TOPK) { eo[r0] = (float)(unsigned)(k0 & 0xFFFFFFFFu); dno[r0] = __uint_as_float((unsigned)(k0 >> 32)); }
        if (r1 < TOPK) { eo[r1] = (float)(unsigned)(k1 & 0xFFFFFFFFu); dno[r1] = __uint_as_float((unsigned)(k1 >> 32)); }
        if (r2 < TOPK) { eo[r2] = (float)(unsigned)(k2 & 0xFFFFFFFFu); dno[r2] = __uint_as_float((unsigned)(k2 >> 32)); }
        if (r3 < TOPK) { eo[r3] = (float)(unsigned)(k3 & 0xFFFFFFFFu); dno[r3] = __uint_as_float((unsigned)(k3 >> 32)); }
    } else {
        // ---- fallback: wave-iterative exact argmin from registers (rare) ----
        ull last = 0ULL;
        for (int k = 0; k < TOPK; ++k) {
            ull best = ~0ULL;
            #pragma unroll
            for (int t = 0; t < 32; ++t) {
                ull key = ((ull)u[t] << 32) | (unsigned)(ln + 64 * t);
                if (key > last && key < best) best = key;
            }
            #pragma unroll
            for (int off = 32; off; off >>= 1) {
                ull o = __shfl_xor(best, off);
                if (o < best) best = o;
            }
            if (ln == 0) {
                eo[k]  = (float)(unsigned)(best & 0xFFFFFFFFu);
                dno[k] = __uint_as_float((unsigned)(best >> 32));
            }
            last = best;
        }
    }
}

// ---------------------------------------------------------------------------
// K2 (v2): edge features -> 32x128 matmul (MFMA bf16) -> LayerNorm -> E.
// Swapped orientation: D = mfma(W_frag, feat_frag) -> D[row=h_low][col=edge].
// Lane (c,g) owns edge e0+c entirely (h = t*16+g*4+j), so:
//   - LayerNorm reduce = 2 shfl_xor pairs (lanes c, c+16, c+32, c+48)
//   - stores are 8 nontemporal dwordx4 per lane (contiguous 16B at h=t*16+g*4)
// bias/gamma/beta reloaded per tile as L1-resident float4s.
// ---------------------------------------------------------------------------
__global__ __launch_bounds__(256) void edge_kernel(
    const float* __restrict__ eidx, const float* __restrict__ dnb,
    const float* __restrict__ We, const float* __restrict__ be,
    const float* __restrict__ ge, const float* __restrict__ bte,
    float* __restrict__ E)
{
    const int lane = threadIdx.x & 63;
    const int c    = lane & 15;        // edge within tile / A-row (h_low)
    const int g    = lane >> 4;        // k-group
    const int wid  = (int)((blockIdx.x * blockDim.x + threadIdx.x) >> 6);
    const int nw   = (int)((gridDim.x * blockDim.x) >> 6);

    // W fragments: lane(c,g) holds A[row=c][k=g*8+e] = We[(g*8+e)*NH + t*16+c]
    short8v W[8];
    #pragma unroll
    for (int t = 0; t < 8; ++t)
        #pragma unroll
        for (int e = 0; e < 8; ++e)
            W[t][e] = f2bf(We[(g * 8 + e) * NH + t * 16 + c]);

    // per-lane feature constants for k = g*8+e
    float fcs[8];
    #pragma unroll
    for (int e = 0; e < 8; ++e) {
        if (g < 2) fcs[e] = expf((float)(2 * e) * -0.57564627f);  // ln(1e4)/16
        else       fcs[e] = (float)((g - 2) * 8 + e) * (20.0f / 15.0f);
    }

    const int ntiles = NB * NL * TOPK / 16;
    for (int tile = wid; tile < ntiles; tile += nw) {
        const int e0   = tile * 16;
        const int edge = e0 + c;
        const float fidx = eidx[edge];
        const float Dv   = dnb[edge];
        const int   row  = edge / TOPK;
        const float d    = fidx - (float)(row & (NL - 1));

        // feature fragment: B[k=g*8+e][col=c] = feature k of edge e0+c
        short8v F;
        if (g == 0) {
            #pragma unroll
            for (int e = 0; e < 8; ++e) F[e] = f2bf(cosf(d * fcs[e]));
        } else if (g == 1) {
            #pragma unroll
            for (int e = 0; e < 8; ++e) F[e] = f2bf(sinf(d * fcs[e]));
        } else {
            #pragma unroll
            for (int e = 0; e < 8; ++e) {
                float tt = (Dv - fcs[e]) * 0.8f;
                F[e] = f2bf(expf(-tt * tt));
            }
        }

        f32x4 acc[8];
        const f32x4 zero = {0.0f, 0.0f, 0.0f, 0.0f};
        #pragma unroll
        for (int t = 0; t < 8; ++t)
            acc[t] = __builtin_amdgcn_mfma_f32_16x16x32_bf16(W[t], F, zero, 0, 0, 0);

        // bias + LN sums (lane owns 32 of edge's 128 values)
        float s = 0.0f, s2 = 0.0f;
        #pragma unroll
        for (int t = 0; t < 8; ++t) {
            const f32x4 b4 = *(const f32x4*)&be[t * 16 + g * 4];
            #pragma unroll
            for (int j = 0; j < 4; ++j) {
                float vv = acc[t][j] + b4[j];
                acc[t][j] = vv;
                s  += vv;
                s2 = fmaf(vv, vv, s2);
            }
        }
        s  += __shfl_xor(s, 16);  s  += __shfl_xor(s, 32);
        s2 += __shfl_xor(s2, 16); s2 += __shfl_xor(s2, 32);
        const float mean = s * (1.0f / 128.0f);
        const float var  = fmaxf(s2 * (1.0f / 128.0f) - mean * mean, 0.0f);
        const float inv  = rsqrtf(var + 1e-5f);

        float* const Eo = E + (size_t)edge * NH;
        #pragma unroll
        for (int t = 0; t < 8; ++t) {
            const f32x4 g4  = *(const f32x4*)&ge [t * 16 + g * 4];
            const f32x4 bt4 = *(const f32x4*)&bte[t * 16 + g * 4];
            f32x4 o;
            #pragma unroll
            for (int j = 0; j < 4; ++j)
                o[j] = (acc[t][j] - mean) * inv * g4[j] + bt4[j];
            __builtin_nontemporal_store(o, (f32x4*)&Eo[t * 16 + g * 4]);
        }
    }
}

// ---------------------------------------------------------------------------
// K3: FUSED dihedral + node matmul + LayerNorm -> V. One wave per node.
// ---------------------------------------------------------------------------
__device__ __forceinline__ void loadPt(const float* XB, int t, float v[3]) {
    int r = t / 3, a = t - 3 * r;
    const float* p = XB + ((size_t)r * 4 + a) * 3;
    v[0] = p[0]; v[1] = p[1]; v[2] = p[2];
}
__device__ __forceinline__ void unit3(float v[3]) {
    float n = sqrtf(v[0]*v[0] + v[1]*v[1] + v[2]*v[2]) + 1e-8f;
    v[0] /= n; v[1] /= n; v[2] /= n;
}
__device__ __forceinline__ void cross3(const float a[3], const float b[3], float o[3]) {
    o[0] = a[1]*b[2] - a[2]*b[1];
    o[1] = a[2]*b[0] - a[0]*b[2];
    o[2] = a[0]*b[1] - a[1]*b[0];
}

__global__ __launch_bounds__(256) void vn_kernel(
    const float* __restrict__ X, const float* __restrict__ Wn,
    const float* __restrict__ bn, const float* __restrict__ gn,
    const float* __restrict__ btn, float* __restrict__ V)
{
    const int ln   = threadIdx.x & 63;
    const int wv   = threadIdx.x >> 6;
    const int node = blockIdx.x * 4 + wv;
    const int b = node >> 11, i = node & (NL - 1);
    const float* XB = X + (size_t)b * NL * 12;

    float fc = 1.0f, fs = 0.0f;                    // pad: cos(0), sin(0)
    if (ln < 3) {
        int t = 3 * i - 1 + ln;
        float an = 0.0f;
        if (t >= 0 && t <= 3 * NL - 4) {
            float p0[3], p1[3], p2[3], p3[3];
            loadPt(XB, t, p0); loadPt(XB, t + 1, p1);
            loadPt(XB, t + 2, p2); loadPt(XB, t + 3, p3);
            float u2[3], u1[3], u0[3];
            for (int cc = 0; cc < 3; ++cc) {
                u2[cc] = p1[cc] - p0[cc];
                u1[cc] = p2[cc] - p1[cc];
                u0[cc] = p3[cc] - p2[cc];
            }
            unit3(u2); unit3(u1); unit3(u0);
            float n2[3], n1[3];
            cross3(u2, u1, n2); cross3(u1, u0, n1);
            unit3(n2); unit3(n1);
            float cosD = n2[0]*n1[0] + n2[1]*n1[1] + n2[2]*n1[2];
            cosD = fminf(fmaxf(cosD, -1.0f + 1e-7f), 1.0f - 1e-7f);
            float sg = u2[0]*n1[0] + u2[1]*n1[1] + u2[2]*n1[2];
            float sgn = (sg > 0.0f) ? 1.0f : ((sg < 0.0f) ? -1.0f : 0.0f);
            an = sgn * acosf(cosD);
        }
        fc = cosf(an); fs = sinf(an);
    }
    float f[6];
    f[0] = __shfl(fc, 0); f[1] = __shfl(fc, 1); f[2] = __shfl(fc, 2);
    f[3] = __shfl(fs, 0); f[4] = __shfl(fs, 1); f[5] = __shfl(fs, 2);

    const int h0 = ln, h1 = ln + 64;
    float a0 = bn[h0], a1 = bn[h1];
    #pragma unroll
    for (int j = 0; j < 6; ++j) {
        a0 = fmaf(f[j], Wn[j * NH + h0], a0);
        a1 = fmaf(f[j], Wn[j * NH + h1], a1);
    }
    float s  = a0 + a1;
    float s2 = fmaf(a0, a0, a1 * a1);
    #pragma unroll
    for (int off = 32; off; off >>= 1) {
        s  += __shfl_xor(s, off);
        s2 += __shfl_xor(s2, off);
    }
    float mean = s * (1.0f / 128.0f);
    float var  = fmaxf(s2 * (1.0f / 128.0f) - mean * mean, 0.0f);
    float inv  = rsqrtf(var + 1e-5f);
    float* o = V + (size_t)node * NH;
    o[h0] = (a0 - mean) * inv * gn[h0] + btn[h0];
    o[h1] = (a1 - mean) * inv * gn[h1] + btn[h1];
}

extern "C" void kernel_launch(void* const* d_in, const int* in_sizes, int n_in,
                              void* d_out, int out_size, void* d_ws, size_t ws_size,
                              hipStream_t stream)
{
    const float* X    = (const float*)d_in[0];
    const float* mask = (const float*)d_in[1];
    const float* Wn   = (const float*)d_in[2];
    const float* bn   = (const float*)d_in[3];
    const float* We   = (const float*)d_in[4];
    const float* be   = (const float*)d_in[5];
    const float* gn   = (const float*)d_in[6];
    const float* btn  = (const float*)d_in[7];
    const float* ge   = (const float*)d_in[8];
    const float* bte  = (const float*)d_in[9];

    float* out = (float*)d_out;
    float* V   = out;                                   // (8,2048,128)
    float* E   = V  + (size_t)NB * NL * NH;             // (8,2048,30,128)
    float* EI  = E  + (size_t)NB * NL * TOPK * NH;      // (8,2048,30) as float

    float4* P  = (float4*)d_ws;                         // SoA (x,y,z,m), 256 KB
    float* dnb = (float*)d_ws + 4 * (size_t)NB * NL;    // D_neighbors scratch

    hipLaunchKernelGGL(xpose_kernel, dim3((NB * NL + 255)/256), dim3(256), 0, stream,
                       X, mask, P);
    // ATTRIBUTION PROBE: topk launched twice (idempotent & deterministic).
    // This round's dur_us = T_total + T_topk; next round drops the dup to
    // read T_topk exactly from the delta.
    hipLaunchKernelGGL(topk_kernel,  dim3(NB * NL / 4),         dim3(256), 0, stream,
                       P, EI, dnb);
    hipLaunchKernelGGL(topk_kernel,  dim3(NB * NL / 4),         dim3(256), 0, stream,
                       P, EI, dnb);
    hipLaunchKernelGGL(vn_kernel,    dim3(NB * NL / 4),         dim3(256), 0, stream,
                       X, Wn, bn, gn, btn, V);
    hipLaunchKernelGGL(edge_kernel,  dim3(1920),                dim3(256), 0, stream,
                       EI, dnb, We, be, ge, bte, E);
}

// Round 9
// 147.491 us; speedup vs baseline: 1.3014x; 1.3014x over previous
//
#include <hip/hip_runtime.h>
#include <cstdint>
#include <cstddef>

#define NB 8
#define NL 2048
#define TOPK 30
#define NH 128
#define CAND_CAP 256

typedef unsigned long long ull;
typedef __attribute__((ext_vector_type(8))) short short8v;   // 8 bf16
typedef __attribute__((ext_vector_type(4))) float f32x4;

__device__ __forceinline__ short f2bf(float f) {
    unsigned int b = __float_as_uint(f);
    b += 0x7fffu + ((b >> 16) & 1u);          // round-to-nearest-even
    return (short)(b >> 16);
}

// ---------------------------------------------------------------------------
// K0: pack CA coords + mask into SoA float4 (x,y,z,m) for coalesced topk loads.
// ---------------------------------------------------------------------------
__global__ __launch_bounds__(256) void xpose_kernel(
    const float* __restrict__ X, const float* __restrict__ mask,
    float4* __restrict__ P)
{
    int t = blockIdx.x * blockDim.x + threadIdx.x;
    if (t >= NB * NL) return;
    const float* p = X + (size_t)t * 12 + 3;
    P[t] = make_float4(p[0], p[1], p[2], mask[t]);
}

// ---------------------------------------------------------------------------
// K1 (v5): one WAVE per row, register-resident, NO histogram.
// (unchanged from R8 — bitonic lane-min threshold, ballot compaction,
// rank-based exact selection; key = (bits<<32)|j == lax.top_k order)
// ---------------------------------------------------------------------------
__global__ __launch_bounds__(256) void topk_kernel(
    const float4* __restrict__ P,
    float* __restrict__ eidx, float* __restrict__ dnb)
{
    __shared__ ull cand[4][CAND_CAP];              // 8 KB

    const int tid = threadIdx.x;
    const int wv  = tid >> 6;
    const int ln  = tid & 63;
    const int row = blockIdx.x * 4 + wv;           // 4 consecutive rows/block
    const int b   = row >> 11;
    const int i   = row & (NL - 1);

    const float4* Pb = P + (size_t)b * NL;
    const float4 pi = Pb[i];
    const float xi = pi.x, yi = pi.y, zi = pi.z, mi = pi.w;

    // ---- P1: distances once; pack mask flag into sign bit ----
    unsigned int u[32];
    float lmax = 0.0f;
    #pragma unroll
    for (int t = 0; t < 32; ++t) {
        const float4 pj = Pb[ln + 64 * t];
        float dx = xi - pj.x;
        float dy = yi - pj.y;
        float dz = zi - pj.z;
        float s = __fadd_rn(__fmul_rn(dx, dx), __fmul_rn(dy, dy));
        s = __fadd_rn(s, __fmul_rn(dz, dz));
        s = __fadd_rn(s, 1e-6f);
        float m2 = __fmul_rn(pj.w, mi);            // binary mask: 0 or 1
        float d  = __fmul_rn(m2, __fsqrt_rn(s));
        u[t] = __float_as_uint(d) | ((m2 == 0.0f) ? 0x80000000u : 0u);
        lmax = fmaxf(lmax, d);
    }
    #pragma unroll
    for (int off = 32; off; off >>= 1) lmax = fmaxf(lmax, __shfl_xor(lmax, off));
    const unsigned int DMB = __float_as_uint(__fadd_rn(lmax, 1.0f));

    // ---- P2: adjusted bits via select + per-lane min ----
    unsigned int umin = 0xFFFFFFFFu;
    #pragma unroll
    for (int t = 0; t < 32; ++t) {
        unsigned int bt = (u[t] & 0x80000000u) ? DMB : u[t];
        u[t] = bt;
        umin = min(umin, bt);
    }

    // ---- P3: bitonic sort of 64 lane-minima -> threshold T at rank 29 ----
    unsigned int v = umin;
    #pragma unroll
    for (int k = 2; k <= 64; k <<= 1) {
        #pragma unroll
        for (int j = k >> 1; j > 0; j >>= 1) {
            unsigned int o = __shfl_xor(v, j);
            bool asc   = ((ln & k) == 0);
            bool lower = ((ln & j) == 0);
            v = (lower == asc) ? min(v, o) : max(v, o);
        }
    }
    const unsigned int T = __shfl(v, TOPK - 1);

    // ---- P4: ordered ballot compaction (index-sorted: t outer, lane inner) ----
    unsigned int base = 0;
    #pragma unroll
    for (int t = 0; t < 32; ++t) {
        bool act = u[t] <= T;
        ull m = __ballot(act);
        if (act) {
            unsigned int pos = base + (unsigned)__popcll(m & ((1ull << ln) - 1ull));
            if (pos < CAND_CAP)
                cand[wv][pos] = ((ull)u[t] << 32) | (unsigned)(ln + 64 * t);
        }
        base += (unsigned)__popcll(m);
    }
    const unsigned int cnt = base;

    float* eo  = eidx + (size_t)row * TOPK;
    float* dno = dnb  + (size_t)row * TOPK;

    if (cnt <= CAND_CAP) {
        // ---- P5: rank-based exact selection ----
        ull k0 = ((unsigned)ln        < cnt) ? cand[wv][ln]        : ~0ULL;
        ull k1 = ((unsigned)ln +  64u < cnt) ? cand[wv][ln +  64]  : ~0ULL;
        ull k2 = ((unsigned)ln + 128u < cnt) ? cand[wv][ln + 128]  : ~0ULL;
        ull k3 = ((unsigned)ln + 192u < cnt) ? cand[wv][ln + 192]  : ~0ULL;
        int r0 = 0, r1 = 0, r2 = 0, r3 = 0;
        for (unsigned int p = 0; p < cnt; ++p) {
            ull kp = cand[wv][p];
            r0 += (kp < k0); r1 += (kp < k1); r2 += (kp < k2); r3 += (kp < k3);
        }
        if (r0 < TOPK) { eo[r0] = (float)(unsigned)(k0 & 0xFFFFFFFFu); dno[r0] = __uint_as_float((unsigned)(k0 >> 32)); }
        if (r1 < TOPK) { eo[r1] = (float)(unsigned)(k1 & 0xFFFFFFFFu); dno[r1] = __uint_as_float((unsigned)(k1 >> 32)); }
        if (r2 < TOPK) { eo[r2] = (float)(unsigned)(k2 & 0xFFFFFFFFu); dno[r2] = __uint_as_float((unsigned)(k2 >> 32)); }
        if (r3 < TOPK) { eo[r3] = (float)(unsigned)(k3 & 0xFFFFFFFFu); dno[r3] = __uint_as_float((unsigned)(k3 >> 32)); }
    } else {
        // ---- fallback: wave-iterative exact argmin from registers (rare) ----
        ull last = 0ULL;
        for (int k = 0; k < TOPK; ++k) {
            ull best = ~0ULL;
            #pragma unroll
            for (int t = 0; t < 32; ++t) {
                ull key = ((ull)u[t] << 32) | (unsigned)(ln + 64 * t);
                if (key > last && key < best) best = key;
            }
            #pragma unroll
            for (int off = 32; off; off >>= 1) {
                ull o = __shfl_xor(best, off);
                if (o < best) best = o;
            }
            if (ln == 0) {
                eo[k]  = (float)(unsigned)(best & 0xFFFFFFFFu);
                dno[k] = __uint_as_float((unsigned)(best >> 32));
            }
            last = best;
        }
    }
}

// ---------------------------------------------------------------------------
// K2 (v2): edge features -> 32x128 matmul (MFMA bf16) -> LayerNorm -> E.
// (unchanged from R8 — swapped orientation, lane owns one edge, dwordx4
// nontemporal stores)
// ---------------------------------------------------------------------------
__global__ __launch_bounds__(256) void edge_kernel(
    const float* __restrict__ eidx, const float* __restrict__ dnb,
    const float* __restrict__ We, const float* __restrict__ be,
    const float* __restrict__ ge, const float* __restrict__ bte,
    float* __restrict__ E)
{
    const int lane = threadIdx.x & 63;
    const int c    = lane & 15;        // edge within tile / A-row (h_low)
    const int g    = lane >> 4;        // k-group
    const int wid  = (int)((blockIdx.x * blockDim.x + threadIdx.x) >> 6);
    const int nw   = (int)((gridDim.x * blockDim.x) >> 6);

    short8v W[8];
    #pragma unroll
    for (int t = 0; t < 8; ++t)
        #pragma unroll
        for (int e = 0; e < 8; ++e)
            W[t][e] = f2bf(We[(g * 8 + e) * NH + t * 16 + c]);

    float fcs[8];
    #pragma unroll
    for (int e = 0; e < 8; ++e) {
        if (g < 2) fcs[e] = expf((float)(2 * e) * -0.57564627f);  // ln(1e4)/16
        else       fcs[e] = (float)((g - 2) * 8 + e) * (20.0f / 15.0f);
    }

    const int ntiles = NB * NL * TOPK / 16;
    for (int tile = wid; tile < ntiles; tile += nw) {
        const int e0   = tile * 16;
        const int edge = e0 + c;
        const float fidx = eidx[edge];
        const float Dv   = dnb[edge];
        const int   row  = edge / TOPK;
        const float d    = fidx - (float)(row & (NL - 1));

        short8v F;
        if (g == 0) {
            #pragma unroll
            for (int e = 0; e < 8; ++e) F[e] = f2bf(cosf(d * fcs[e]));
        } else if (g == 1) {
            #pragma unroll
            for (int e = 0; e < 8; ++e) F[e] = f2bf(sinf(d * fcs[e]));
        } else {
            #pragma unroll
            for (int e = 0; e < 8; ++e) {
                float tt = (Dv - fcs[e]) * 0.8f;
                F[e] = f2bf(expf(-tt * tt));
            }
        }

        f32x4 acc[8];
        const f32x4 zero = {0.0f, 0.0f, 0.0f, 0.0f};
        #pragma unroll
        for (int t = 0; t < 8; ++t)
            acc[t] = __builtin_amdgcn_mfma_f32_16x16x32_bf16(W[t], F, zero, 0, 0, 0);

        float s = 0.0f, s2 = 0.0f;
        #pragma unroll
        for (int t = 0; t < 8; ++t) {
            const f32x4 b4 = *(const f32x4*)&be[t * 16 + g * 4];
            #pragma unroll
            for (int j = 0; j < 4; ++j) {
                float vv = acc[t][j] + b4[j];
                acc[t][j] = vv;
                s  += vv;
                s2 = fmaf(vv, vv, s2);
            }
        }
        s  += __shfl_xor(s, 16);  s  += __shfl_xor(s, 32);
        s2 += __shfl_xor(s2, 16); s2 += __shfl_xor(s2, 32);
        const float mean = s * (1.0f / 128.0f);
        const float var  = fmaxf(s2 * (1.0f / 128.0f) - mean * mean, 0.0f);
        const float inv  = rsqrtf(var + 1e-5f);

        float* const Eo = E + (size_t)edge * NH;
        #pragma unroll
        for (int t = 0; t < 8; ++t) {
            const f32x4 g4  = *(const f32x4*)&ge [t * 16 + g * 4];
            const f32x4 bt4 = *(const f32x4*)&bte[t * 16 + g * 4];
            f32x4 o;
            #pragma unroll
            for (int j = 0; j < 4; ++j)
                o[j] = (acc[t][j] - mean) * inv * g4[j] + bt4[j];
            __builtin_nontemporal_store(o, (f32x4*)&Eo[t * 16 + g * 4]);
        }
    }
}

// ---------------------------------------------------------------------------
// K3: FUSED dihedral + node matmul + LayerNorm -> V. One wave per node.
// (unchanged from R8)
// ---------------------------------------------------------------------------
__device__ __forceinline__ void loadPt(const float* XB, int t, float v[3]) {
    int r = t / 3, a = t - 3 * r;
    const float* p = XB + ((size_t)r * 4 + a) * 3;
    v[0] = p[0]; v[1] = p[1]; v[2] = p[2];
}
__device__ __forceinline__ void unit3(float v[3]) {
    float n = sqrtf(v[0]*v[0] + v[1]*v[1] + v[2]*v[2]) + 1e-8f;
    v[0] /= n; v[1] /= n; v[2] /= n;
}
__device__ __forceinline__ void cross3(const float a[3], const float b[3], float o[3]) {
    o[0] = a[1]*b[2] - a[2]*b[1];
    o[1] = a[2]*b[0] - a[0]*b[2];
    o[2] = a[0]*b[1] - a[1]*b[0];
}

__global__ __launch_bounds__(256) void vn_kernel(
    const float* __restrict__ X, const float* __restrict__ Wn,
    const float* __restrict__ bn, const float* __restrict__ gn,
    const float* __restrict__ btn, float* __restrict__ V)
{
    const int ln   = threadIdx.x & 63;
    const int wv   = threadIdx.x >> 6;
    const int node = blockIdx.x * 4 + wv;
    const int b = node >> 11, i = node & (NL - 1);
    const float* XB = X + (size_t)b * NL * 12;

    float fc = 1.0f, fs = 0.0f;                    // pad: cos(0), sin(0)
    if (ln < 3) {
        int t = 3 * i - 1 + ln;
        float an = 0.0f;
        if (t >= 0 && t <= 3 * NL - 4) {
            float p0[3], p1[3], p2[3], p3[3];
            loadPt(XB, t, p0); loadPt(XB, t + 1, p1);
            loadPt(XB, t + 2, p2); loadPt(XB, t + 3, p3);
            float u2[3], u1[3], u0[3];
            for (int cc = 0; cc < 3; ++cc) {
                u2[cc] = p1[cc] - p0[cc];
                u1[cc] = p2[cc] - p1[cc];
                u0[cc] = p3[cc] - p2[cc];
            }
            unit3(u2); unit3(u1); unit3(u0);
            float n2[3], n1[3];
            cross3(u2, u1, n2); cross3(u1, u0, n1);
            unit3(n2); unit3(n1);
            float cosD = n2[0]*n1[0] + n2[1]*n1[1] + n2[2]*n1[2];
            cosD = fminf(fmaxf(cosD, -1.0f + 1e-7f), 1.0f - 1e-7f);
            float sg = u2[0]*n1[0] + u2[1]*n1[1] + u2[2]*n1[2];
            float sgn = (sg > 0.0f) ? 1.0f : ((sg < 0.0f) ? -1.0f : 0.0f);
            an = sgn * acosf(cosD);
        }
        fc = cosf(an); fs = sinf(an);
    }
    float f[6];
    f[0] = __shfl(fc, 0); f[1] = __shfl(fc, 1); f[2] = __shfl(fc, 2);
    f[3] = __shfl(fs, 0); f[4] = __shfl(fs, 1); f[5] = __shfl(fs, 2);

    const int h0 = ln, h1 = ln + 64;
    float a0 = bn[h0], a1 = bn[h1];
    #pragma unroll
    for (int j = 0; j < 6; ++j) {
        a0 = fmaf(f[j], Wn[j * NH + h0], a0);
        a1 = fmaf(f[j], Wn[j * NH + h1], a1);
    }
    float s  = a0 + a1;
    float s2 = fmaf(a0, a0, a1 * a1);
    #pragma unroll
    for (int off = 32; off; off >>= 1) {
        s  += __shfl_xor(s, off);
        s2 += __shfl_xor(s2, off);
    }
    float mean = s * (1.0f / 128.0f);
    float var  = fmaxf(s2 * (1.0f / 128.0f) - mean * mean, 0.0f);
    float inv  = rsqrtf(var + 1e-5f);
    float* o = V + (size_t)node * NH;
    o[h0] = (a0 - mean) * inv * gn[h0] + btn[h0];
    o[h1] = (a1 - mean) * inv * gn[h1] + btn[h1];
}

extern "C" void kernel_launch(void* const* d_in, const int* in_sizes, int n_in,
                              void* d_out, int out_size, void* d_ws, size_t ws_size,
                              hipStream_t stream)
{
    const float* X    = (const float*)d_in[0];
    const float* mask = (const float*)d_in[1];
    const float* Wn   = (const float*)d_in[2];
    const float* bn   = (const float*)d_in[3];
    const float* We   = (const float*)d_in[4];
    const float* be   = (const float*)d_in[5];
    const float* gn   = (const float*)d_in[6];
    const float* btn  = (const float*)d_in[7];
    const float* ge   = (const float*)d_in[8];
    const float* bte  = (const float*)d_in[9];

    float* out = (float*)d_out;
    float* V   = out;                                   // (8,2048,128)
    float* E   = V  + (size_t)NB * NL * NH;             // (8,2048,30,128)
    float* EI  = E  + (size_t)NB * NL * TOPK * NH;      // (8,2048,30) as float

    float4* P  = (float4*)d_ws;                         // SoA (x,y,z,m), 256 KB
    float* dnb = (float*)d_ws + 4 * (size_t)NB * NL;    // D_neighbors scratch

    // ATTRIBUTION READ-OUT: R8 ran topk TWICE; this round is byte-identical
    // except the duplicate is removed. T_topk5 = dur_us(R8) - dur_us(R9).
    hipLaunchKernelGGL(xpose_kernel, dim3((NB * NL + 255)/256), dim3(256), 0, stream,
                       X, mask, P);
    hipLaunchKernelGGL(topk_kernel,  dim3(NB * NL / 4),         dim3(256), 0, stream,
                       P, EI, dnb);
    hipLaunchKernelGGL(vn_kernel,    dim3(NB * NL / 4),         dim3(256), 0, stream,
                       X, Wn, bn, gn, btn, V);
    hipLaunchKernelGGL(edge_kernel,  dim3(1920),                dim3(256), 0, stream,
                       EI, dnb, We, be, ge, bte, E);
}